// Round 4
// baseline (62.044 us; speedup 1.0000x reference)
//
#include <hip/hip_runtime.h>
#include <math.h>

#define BB 32
#define HH 256
#define NN 8192
#define CC 16                 // chunks over N
#define CHUNK (NN / CC)       // 512 points per chunk
#define P 8                   // planes per thread in score kernel
#define SUB (CHUNK / P)       // 64 points per sub-range

// ws layout (floats):
//   planes : BB*HH*4 = 32768 floats at 0      (float4 per plane)
//   loss   : BB*HH   =  8192 floats at 32768
//   cnt    : BB ints at float-offset 40960
//   partial: BB*CC*HH floats at 41024 (256B aligned)
#define WS_LOSS_F   ((size_t)BB * HH * 4)
#define WS_CNT_F    (WS_LOSS_F + BB * HH)
#define WS_PART_F   (WS_CNT_F + 64)

__global__ __launch_bounds__(64) void fit_planes_kernel(
    const float* __restrict__ pts, const float* __restrict__ target,
    const int* __restrict__ sidx, float* __restrict__ ws, int* __restrict__ cnt) {
  int b = blockIdx.y;
  int h = blockIdx.x * 64 + threadIdx.x;
  if (blockIdx.x == 0 && threadIdx.x == 0) cnt[b] = 0;  // reset arrival counter
  long base = ((long)b * HH + h) * 3;
  int i0 = sidx[base + 0], i1 = sidx[base + 1], i2 = sidx[base + 2];
  const float* pb = pts + (long)b * NN * 3;
  float p0x = pb[3 * i0], p0y = pb[3 * i0 + 1], p0z = pb[3 * i0 + 2];
  float p1x = pb[3 * i1], p1y = pb[3 * i1 + 1], p1z = pb[3 * i1 + 2];
  float p2x = pb[3 * i2], p2y = pb[3 * i2 + 1], p2z = pb[3 * i2 + 2];
  float v1x = p1x - p0x, v1y = p1y - p0y, v1z = p1z - p0z;
  float v2x = p2x - p0x, v2y = p2y - p0y, v2z = p2z - p0z;
  // cross product with explicit non-FMA ops: degenerate triples must give
  // EXACT zero to match numpy's all_zero replacement path.
  float nx = __fsub_rn(__fmul_rn(v1y, v2z), __fmul_rn(v1z, v2y));
  float ny = __fsub_rn(__fmul_rn(v1z, v2x), __fmul_rn(v1x, v2z));
  float nz = __fsub_rn(__fmul_rn(v1x, v2y), __fmul_rn(v1y, v2x));
  float d = -(__fmul_rn(nx, p0x) + __fmul_rn(ny, p0y) + __fmul_rn(nz, p0z));
  if (nx == 0.0f && ny == 0.0f && nz == 0.0f && d == 0.0f) {
    nx = 1.0f; ny = 1.0f; nz = 1.0f; d = 1.0f;
  }
  float norm = sqrtf(nx * nx + ny * ny + nz * nz);
  nx /= norm; ny /= norm; nz /= norm; d /= norm;
  ((float4*)ws)[b * HH + h] = make_float4(nx, ny, nz, d);
  float tx = target[b * 3], ty = target[b * 3 + 1], tz = target[b * 3 + 2];
  float lm = (nx - tx) * (nx - tx) + (ny - ty) * (ny - ty) + (nz - tz) * (nz - tz);
  float lp = (nx + tx) * (nx + tx) + (ny + ty) * (ny + ty) + (nz + tz) * (nz + tz);
  ws[WS_LOSS_F + b * HH + h] = fminf(lm, lp);
}

__global__ __launch_bounds__(HH) void score_finalize_kernel(
    const float* __restrict__ pts, const float* __restrict__ ws,
    float* __restrict__ partial, int* __restrict__ cnt, float* __restrict__ out) {
  const int chunk = blockIdx.x, b = blockIdx.y;
  const int h = threadIdx.x;
  __shared__ float4 smp[CHUNK * 3 / 4];   // 6 KB chunk points
  __shared__ float scorepad[HH * 9];      // 9 KB padded reduce pad
  __shared__ float sv[HH];
  __shared__ int si[HH];
  __shared__ float s1[HH];
  __shared__ float s2[HH];
  __shared__ int isLast;

  // async global->LDS stage (wave-contiguous dests; drains at the barrier)
  const float4* src4 =
      (const float4*)(pts + ((long)b * NN + (long)chunk * CHUNK) * 3);
  for (int j = h; j < CHUNK * 3 / 4; j += HH) {
    __builtin_amdgcn_global_load_lds(src4 + j, &smp[j], 16, 0, 0);
  }

  // load P planes (pre-scaled by sqrt(50*log2 e)) while the stage is in flight
  const float SC = 8.4932180028801371f;  // sqrt(72.13475204444817)
  const int pid = h & 31;
  const int s = h >> 5;  // point sub-range
  float4 pls[P];
#pragma unroll
  for (int k = 0; k < P; ++k) {
    float4 q = ((const float4*)ws)[b * HH + pid + (k << 5)];
    pls[k] = make_float4(q.x * SC, q.y * SC, q.z * SC, q.w * SC);
  }
  __syncthreads();

  // score: 64 points x 8 planes per thread
  float acc[P];
#pragma unroll
  for (int k = 0; k < P; ++k) acc[k] = 0.f;
  const int sbase = s * (SUB * 3 / 4);  // 48 float4 per sub-range
#pragma unroll 2
  for (int g = 0; g < SUB / 4; ++g) {  // 4 points per iter (broadcast reads)
    float4 v0 = smp[sbase + 3 * g + 0];
    float4 v1 = smp[sbase + 3 * g + 1];
    float4 v2 = smp[sbase + 3 * g + 2];
#pragma unroll
    for (int k = 0; k < P; ++k) {
      float4 q = pls[k];
      float t0 = fmaf(q.x, v0.x, fmaf(q.y, v0.y, fmaf(q.z, v0.z, q.w)));
      float t1 = fmaf(q.x, v0.w, fmaf(q.y, v1.x, fmaf(q.z, v1.y, q.w)));
      float t2 = fmaf(q.x, v1.z, fmaf(q.y, v1.w, fmaf(q.z, v2.x, q.w)));
      float t3 = fmaf(q.x, v2.y, fmaf(q.y, v2.z, fmaf(q.z, v2.w, q.w)));
      float e0 = __builtin_amdgcn_exp2f(-(t0 * t0));
      float e1 = __builtin_amdgcn_exp2f(-(t1 * t1));
      float e2 = __builtin_amdgcn_exp2f(-(t2 * t2));
      float e3 = __builtin_amdgcn_exp2f(-(t3 * t3));
      acc[k] += (e0 + e1) + (e2 + e3);
    }
  }

  // in-block reduce across sub-ranges (stride-9 pad: conflict-free)
#pragma unroll
  for (int k = 0; k < P; ++k) scorepad[(pid + (k << 5)) * 9 + s] = acc[k];
  __syncthreads();
  float rowsum = 0.f;
#pragma unroll
  for (int j = 0; j < P; ++j) rowsum += scorepad[h * 9 + j];
  partial[((long)b * CC + chunk) * HH + h] = rowsum;

  // ---- last-block-per-batch finalize (threadfence reduction pattern) ----
  __threadfence();
  __syncthreads();
  if (h == 0) {
    int old = atomicAdd(&cnt[b], 1);
    isLast = (old == CC - 1) ? 1 : 0;
  }
  __syncthreads();
  if (!isLast) return;
  __threadfence();  // acquire: all batch-b partial rows now visible

  const float* lossArr = ws + WS_LOSS_F;
  const float* prow = partial + (long)b * CC * HH + h;
  float score = 0.f;
#pragma unroll
  for (int c = 0; c < CC; ++c) score += prow[(long)c * HH];
  float l = lossArr[b * HH + h];

  sv[h] = score; si[h] = h;
  __syncthreads();
  // argmax with first-index tie-break (matches jnp.argmax)
  for (int off = HH / 2; off > 0; off >>= 1) {
    if (h < off) {
      float o = sv[h + off]; int oi = si[h + off];
      if (o > sv[h] || (o == sv[h] && oi < si[h])) { sv[h] = o; si[h] = oi; }
    }
    __syncthreads();
  }
  float m = sv[0];
  int mi = si[0];
  __syncthreads();
  const float HL = 0.72134752044448170f;  // 0.5 * log2(e)
  float wv = __builtin_amdgcn_exp2f(HL * (score - m));
  s1[h] = wv; s2[h] = wv * l;
  __syncthreads();
  for (int off = HH / 2; off > 0; off >>= 1) {
    if (h < off) { s1[h] += s1[h + off]; s2[h] += s2[h + off]; }
    __syncthreads();
  }
  if (h == 0) {
    out[b] = s2[0] / s1[0];                 // exp_loss
    out[BB + b] = lossArr[b * HH + mi];     // top_loss
    float4 p = ((const float4*)ws)[b * HH + mi];
    out[2 * BB + b * 3 + 0] = p.x;          // pred
    out[2 * BB + b * 3 + 1] = p.y;
    out[2 * BB + b * 3 + 2] = p.z;
  }
}

extern "C" void kernel_launch(void* const* d_in, const int* in_sizes, int n_in,
                              void* d_out, int out_size, void* d_ws, size_t ws_size,
                              hipStream_t stream) {
  const float* pts = (const float*)d_in[0];
  const float* target = (const float*)d_in[1];
  const int* sidx = (const int*)d_in[2];
  float* out = (float*)d_out;
  float* ws = (float*)d_ws;
  int* cnt = (int*)(ws + WS_CNT_F);
  float* partial = ws + WS_PART_F;

  fit_planes_kernel<<<dim3(HH / 64, BB), 64, 0, stream>>>(pts, target, sidx, ws, cnt);
  score_finalize_kernel<<<dim3(CC, BB), HH, 0, stream>>>(pts, ws, partial, cnt, out);
}

// Round 5
// 23.670 us; speedup vs baseline: 2.6212x; 2.6212x over previous
//
#include <hip/hip_runtime.h>
#include <math.h>

#define BB 32
#define HH 256
#define NN 8192
#define CC 32                 // chunks over N
#define CHUNK (NN / CC)       // 256 points per chunk
#define P 8                   // planes per thread in score kernel
#define SUB (CHUNK / P)       // 32 points per sub-range

// ws layout (floats):
//   planes : BB*HH*4 = 32768 floats at 0      (float4 per plane)
//   loss   : BB*HH   =  8192 floats at 32768
//   partial: BB*CC*HH floats at 40960
#define WS_LOSS_F ((size_t)BB * HH * 4)
#define WS_PART_F (WS_LOSS_F + (size_t)BB * HH)

// K1: per (chunk, batch) block — redundantly fit all 256 planes of the batch
// into LDS (1 plane/thread, scattered L2-hit gather), score the chunk,
// write one partial row. NO cross-block sync, NO fences (rounds 2/4 lesson).
__global__ __launch_bounds__(HH) void score_kernel(
    const float* __restrict__ pts, const float* __restrict__ target,
    const int* __restrict__ sidx, float* __restrict__ ws,
    float* __restrict__ partial) {
  const int chunk = blockIdx.x, b = blockIdx.y;
  const int h = threadIdx.x;
  __shared__ float4 smp[CHUNK * 3 / 4];   // 3 KB chunk points
  __shared__ float4 plane_lds[HH];        // 4 KB planes (unscaled)
  __shared__ float scorepad[HH * 9];      // 9 KB padded reduce pad

  // async global->LDS stage of this chunk's points (drains at the barrier)
  const float4* src4 =
      (const float4*)(pts + ((long)b * NN + (long)chunk * CHUNK) * 3);
  if (h < CHUNK * 3 / 4) {
    __builtin_amdgcn_global_load_lds(src4 + h, &smp[h], 16, 0, 0);
  }

  // ---- fit plane h of batch b (scattered loads; L2-resident pts) ----
  long ibase = ((long)b * HH + h) * 3;
  int i0 = sidx[ibase], i1 = sidx[ibase + 1], i2 = sidx[ibase + 2];
  const float* pb = pts + (long)b * NN * 3;
  float p0x = pb[3 * i0], p0y = pb[3 * i0 + 1], p0z = pb[3 * i0 + 2];
  float p1x = pb[3 * i1], p1y = pb[3 * i1 + 1], p1z = pb[3 * i1 + 2];
  float p2x = pb[3 * i2], p2y = pb[3 * i2 + 1], p2z = pb[3 * i2 + 2];
  float v1x = p1x - p0x, v1y = p1y - p0y, v1z = p1z - p0z;
  float v2x = p2x - p0x, v2y = p2y - p0y, v2z = p2z - p0z;
  // explicit non-FMA cross product: degenerate triples must give EXACT zero
  // to match numpy's all_zero replacement path.
  float nx = __fsub_rn(__fmul_rn(v1y, v2z), __fmul_rn(v1z, v2y));
  float ny = __fsub_rn(__fmul_rn(v1z, v2x), __fmul_rn(v1x, v2z));
  float nz = __fsub_rn(__fmul_rn(v1x, v2y), __fmul_rn(v1y, v2x));
  float d = -(__fmul_rn(nx, p0x) + __fmul_rn(ny, p0y) + __fmul_rn(nz, p0z));
  if (nx == 0.0f && ny == 0.0f && nz == 0.0f && d == 0.0f) {
    nx = 1.0f; ny = 1.0f; nz = 1.0f; d = 1.0f;
  }
  float norm = sqrtf(nx * nx + ny * ny + nz * nz);
  nx /= norm; ny /= norm; nz /= norm; d /= norm;
  plane_lds[h] = make_float4(nx, ny, nz, d);

  // one block per batch persists planes + loss for the finalize kernel
  if (chunk == 0) {
    ((float4*)ws)[b * HH + h] = make_float4(nx, ny, nz, d);
    float tx = target[b * 3], ty = target[b * 3 + 1], tz = target[b * 3 + 2];
    float lm = (nx - tx) * (nx - tx) + (ny - ty) * (ny - ty) + (nz - tz) * (nz - tz);
    float lp = (nx + tx) * (nx + tx) + (ny + ty) * (ny + ty) + (nz + tz) * (nz + tz);
    ws[WS_LOSS_F + b * HH + h] = fminf(lm, lp);
  }
  __syncthreads();  // planes in LDS + points staged

  // ---- load P planes, pre-scaled by sqrt(50*log2 e) ----
  const float SC = 8.4932180028801371f;
  const int pid = h & 31;
  const int s = h >> 5;  // point sub-range
  float4 pls[P];
#pragma unroll
  for (int k = 0; k < P; ++k) {
    float4 q = plane_lds[pid + (k << 5)];
    pls[k] = make_float4(q.x * SC, q.y * SC, q.z * SC, q.w * SC);
  }

  // ---- score: 32 points x 8 planes per thread (broadcast LDS reads) ----
  float acc[P];
#pragma unroll
  for (int k = 0; k < P; ++k) acc[k] = 0.f;
  const int sbase = s * (SUB * 3 / 4);  // 24 float4 per sub-range
#pragma unroll 2
  for (int g = 0; g < SUB / 4; ++g) {  // 4 points per iter
    float4 v0 = smp[sbase + 3 * g + 0];
    float4 v1 = smp[sbase + 3 * g + 1];
    float4 v2 = smp[sbase + 3 * g + 2];
#pragma unroll
    for (int k = 0; k < P; ++k) {
      float4 q = pls[k];
      float t0 = fmaf(q.x, v0.x, fmaf(q.y, v0.y, fmaf(q.z, v0.z, q.w)));
      float t1 = fmaf(q.x, v0.w, fmaf(q.y, v1.x, fmaf(q.z, v1.y, q.w)));
      float t2 = fmaf(q.x, v1.z, fmaf(q.y, v1.w, fmaf(q.z, v2.x, q.w)));
      float t3 = fmaf(q.x, v2.y, fmaf(q.y, v2.z, fmaf(q.z, v2.w, q.w)));
      float e0 = __builtin_amdgcn_exp2f(-(t0 * t0));
      float e1 = __builtin_amdgcn_exp2f(-(t1 * t1));
      float e2 = __builtin_amdgcn_exp2f(-(t2 * t2));
      float e3 = __builtin_amdgcn_exp2f(-(t3 * t3));
      acc[k] += (e0 + e1) + (e2 + e3);
    }
  }

  // ---- in-block reduce across sub-ranges (stride-9 pad, conflict-free) ----
#pragma unroll
  for (int k = 0; k < P; ++k) scorepad[(pid + (k << 5)) * 9 + s] = acc[k];
  __syncthreads();
  float rowsum = 0.f;
#pragma unroll
  for (int j = 0; j < P; ++j) rowsum += scorepad[h * 9 + j];
  partial[((long)b * CC + chunk) * HH + h] = rowsum;
}

__global__ __launch_bounds__(HH) void finalize_kernel(
    const float* __restrict__ ws, float* __restrict__ out) {
  int b = blockIdx.x, h = threadIdx.x;
  const float* lossArr = ws + WS_LOSS_F;
  const float* partial = ws + WS_PART_F;
  float s = 0.f;
#pragma unroll
  for (int c = 0; c < CC; ++c) s += partial[((long)b * CC + c) * HH + h];
  float l = lossArr[b * HH + h];

  __shared__ float sv[HH];
  __shared__ int si[HH];
  __shared__ float s1[HH];
  __shared__ float s2[HH];
  sv[h] = s; si[h] = h;
  __syncthreads();
  // argmax with first-index tie-break (matches jnp.argmax)
  for (int off = HH / 2; off > 0; off >>= 1) {
    if (h < off) {
      float o = sv[h + off]; int oi = si[h + off];
      if (o > sv[h] || (o == sv[h] && oi < si[h])) { sv[h] = o; si[h] = oi; }
    }
    __syncthreads();
  }
  float m = sv[0];
  int mi = si[0];
  __syncthreads();
  const float HL = 0.72134752044448170f;  // 0.5 * log2(e)
  float wv = __builtin_amdgcn_exp2f(HL * (s - m));
  s1[h] = wv; s2[h] = wv * l;
  __syncthreads();
  for (int off = HH / 2; off > 0; off >>= 1) {
    if (h < off) { s1[h] += s1[h + off]; s2[h] += s2[h + off]; }
    __syncthreads();
  }
  if (h == 0) {
    out[b] = s2[0] / s1[0];                 // exp_loss
    out[BB + b] = lossArr[b * HH + mi];     // top_loss
    float4 p = ((const float4*)ws)[b * HH + mi];
    out[2 * BB + b * 3 + 0] = p.x;          // pred
    out[2 * BB + b * 3 + 1] = p.y;
    out[2 * BB + b * 3 + 2] = p.z;
  }
}

extern "C" void kernel_launch(void* const* d_in, const int* in_sizes, int n_in,
                              void* d_out, int out_size, void* d_ws, size_t ws_size,
                              hipStream_t stream) {
  const float* pts = (const float*)d_in[0];
  const float* target = (const float*)d_in[1];
  const int* sidx = (const int*)d_in[2];
  float* out = (float*)d_out;
  float* ws = (float*)d_ws;
  float* partial = ws + WS_PART_F;

  score_kernel<<<dim3(CC, BB), HH, 0, stream>>>(pts, target, sidx, ws, partial);
  finalize_kernel<<<BB, HH, 0, stream>>>(ws, out);
}

// Round 6
// 22.948 us; speedup vs baseline: 2.7037x; 1.0315x over previous
//
#include <hip/hip_runtime.h>
#include <math.h>

#define BB 32
#define HH 256
#define NN 8192
#define CC 16                 // chunks over N
#define CHUNK (NN / CC)       // 512 points per chunk
#define P 8                   // planes per thread in score kernel
#define SUB (CHUNK / P)       // 64 points per sub-range

// ws layout (floats):
//   planes : BB*HH*4 = 32768 floats at 0      (float4 per plane)
//   loss   : BB*HH   =  8192 floats at 32768
//   partial: BB*CC*HH floats at 40960
#define WS_LOSS_F ((size_t)BB * HH * 4)
#define WS_PART_F (WS_LOSS_F + (size_t)BB * HH)

// K1: per (chunk, batch) block — redundantly fit all 256 planes of the batch
// into LDS (1 plane/thread, scattered L2-hit gather), score the chunk,
// write one partial row. NO cross-block sync, NO fences (rounds 2/4 lesson).
__global__ __launch_bounds__(HH) void score_kernel(
    const float* __restrict__ pts, const float* __restrict__ target,
    const int* __restrict__ sidx, float* __restrict__ ws,
    float* __restrict__ partial) {
  const int chunk = blockIdx.x, b = blockIdx.y;
  const int h = threadIdx.x;
  __shared__ float4 smp[CHUNK * 3 / 4];   // 6 KB chunk points
  __shared__ float4 plane_lds[HH];        // 4 KB planes (unscaled)
  __shared__ float scorepad[HH * 9];      // 9 KB padded reduce pad

  // async global->LDS stage of this chunk's points (drains at the barrier)
  const float4* src4 =
      (const float4*)(pts + ((long)b * NN + (long)chunk * CHUNK) * 3);
#pragma unroll
  for (int j = h; j < CHUNK * 3 / 4; j += HH) {
    __builtin_amdgcn_global_load_lds(src4 + j, &smp[j], 16, 0, 0);
  }

  // ---- fit plane h of batch b (scattered loads; L2-resident pts) ----
  long ibase = ((long)b * HH + h) * 3;
  int i0 = sidx[ibase], i1 = sidx[ibase + 1], i2 = sidx[ibase + 2];
  const float* pb = pts + (long)b * NN * 3;
  float p0x = pb[3 * i0], p0y = pb[3 * i0 + 1], p0z = pb[3 * i0 + 2];
  float p1x = pb[3 * i1], p1y = pb[3 * i1 + 1], p1z = pb[3 * i1 + 2];
  float p2x = pb[3 * i2], p2y = pb[3 * i2 + 1], p2z = pb[3 * i2 + 2];
  float v1x = p1x - p0x, v1y = p1y - p0y, v1z = p1z - p0z;
  float v2x = p2x - p0x, v2y = p2y - p0y, v2z = p2z - p0z;
  // explicit non-FMA cross product: degenerate triples must give EXACT zero
  // to match numpy's all_zero replacement path.
  float nx = __fsub_rn(__fmul_rn(v1y, v2z), __fmul_rn(v1z, v2y));
  float ny = __fsub_rn(__fmul_rn(v1z, v2x), __fmul_rn(v1x, v2z));
  float nz = __fsub_rn(__fmul_rn(v1x, v2y), __fmul_rn(v1y, v2x));
  float d = -(__fmul_rn(nx, p0x) + __fmul_rn(ny, p0y) + __fmul_rn(nz, p0z));
  if (nx == 0.0f && ny == 0.0f && nz == 0.0f && d == 0.0f) {
    nx = 1.0f; ny = 1.0f; nz = 1.0f; d = 1.0f;
  }
  float norm = sqrtf(nx * nx + ny * ny + nz * nz);
  nx /= norm; ny /= norm; nz /= norm; d /= norm;
  plane_lds[h] = make_float4(nx, ny, nz, d);

  // one block per batch persists planes + loss for the finalize kernel
  if (chunk == 0) {
    ((float4*)ws)[b * HH + h] = make_float4(nx, ny, nz, d);
    float tx = target[b * 3], ty = target[b * 3 + 1], tz = target[b * 3 + 2];
    float lm = (nx - tx) * (nx - tx) + (ny - ty) * (ny - ty) + (nz - tz) * (nz - tz);
    float lp = (nx + tx) * (nx + tx) + (ny + ty) * (ny + ty) + (nz + tz) * (nz + tz);
    ws[WS_LOSS_F + b * HH + h] = fminf(lm, lp);
  }
  __syncthreads();  // planes in LDS + points staged

  // ---- load P planes, pre-scaled by sqrt(50*log2 e) ----
  const float SC = 8.4932180028801371f;
  const int pid = h & 31;
  const int s = h >> 5;  // point sub-range
  float4 pls[P];
#pragma unroll
  for (int k = 0; k < P; ++k) {
    float4 q = plane_lds[pid + (k << 5)];
    pls[k] = make_float4(q.x * SC, q.y * SC, q.z * SC, q.w * SC);
  }

  // ---- score: 64 points x 8 planes per thread (broadcast LDS reads) ----
  float acc[P];
#pragma unroll
  for (int k = 0; k < P; ++k) acc[k] = 0.f;
  const int sbase = s * (SUB * 3 / 4);  // 48 float4 per sub-range
#pragma unroll 4
  for (int g = 0; g < SUB / 4; ++g) {  // 4 points per iter
    float4 v0 = smp[sbase + 3 * g + 0];
    float4 v1 = smp[sbase + 3 * g + 1];
    float4 v2 = smp[sbase + 3 * g + 2];
#pragma unroll
    for (int k = 0; k < P; ++k) {
      float4 q = pls[k];
      float t0 = fmaf(q.x, v0.x, fmaf(q.y, v0.y, fmaf(q.z, v0.z, q.w)));
      float t1 = fmaf(q.x, v0.w, fmaf(q.y, v1.x, fmaf(q.z, v1.y, q.w)));
      float t2 = fmaf(q.x, v1.z, fmaf(q.y, v1.w, fmaf(q.z, v2.x, q.w)));
      float t3 = fmaf(q.x, v2.y, fmaf(q.y, v2.z, fmaf(q.z, v2.w, q.w)));
      float e0 = __builtin_amdgcn_exp2f(-(t0 * t0));
      float e1 = __builtin_amdgcn_exp2f(-(t1 * t1));
      float e2 = __builtin_amdgcn_exp2f(-(t2 * t2));
      float e3 = __builtin_amdgcn_exp2f(-(t3 * t3));
      acc[k] += (e0 + e1) + (e2 + e3);
    }
  }

  // ---- in-block reduce across sub-ranges (stride-9 pad, conflict-free) ----
#pragma unroll
  for (int k = 0; k < P; ++k) scorepad[(pid + (k << 5)) * 9 + s] = acc[k];
  __syncthreads();
  float rowsum = 0.f;
#pragma unroll
  for (int j = 0; j < P; ++j) rowsum += scorepad[h * 9 + j];
  partial[((long)b * CC + chunk) * HH + h] = rowsum;
}

__global__ __launch_bounds__(HH) void finalize_kernel(
    const float* __restrict__ ws, float* __restrict__ out) {
  int b = blockIdx.x, h = threadIdx.x;
  const float* lossArr = ws + WS_LOSS_F;
  const float* partial = ws + WS_PART_F;
  float s = 0.f;
#pragma unroll
  for (int c = 0; c < CC; ++c) s += partial[((long)b * CC + c) * HH + h];
  float l = lossArr[b * HH + h];

  __shared__ float redv[4];
  __shared__ int redi[4];
  __shared__ float sw[4], swl[4];

  // ---- wave-level argmax via shuffles (first-index tie-break) ----
  float v = s; int idx = h;
#pragma unroll
  for (int o = 32; o > 0; o >>= 1) {
    float ov = __shfl_xor(v, o);
    int oi = __shfl_xor(idx, o);
    if (ov > v || (ov == v && oi < idx)) { v = ov; idx = oi; }
  }
  const int wid = h >> 6;
  if ((h & 63) == 0) { redv[wid] = v; redi[wid] = idx; }
  __syncthreads();
  float m = redv[0]; int mi = redi[0];
#pragma unroll
  for (int w = 1; w < 4; ++w) {
    float ov = redv[w]; int oi = redi[w];
    if (ov > m || (ov == m && oi < mi)) { m = ov; mi = oi; }
  }

  // ---- softmax sums via shuffles ----
  const float HL = 0.72134752044448170f;  // 0.5 * log2(e)
  float wv = __builtin_amdgcn_exp2f(HL * (s - m));
  float wl = wv * l;
#pragma unroll
  for (int o = 32; o > 0; o >>= 1) {
    wv += __shfl_xor(wv, o);
    wl += __shfl_xor(wl, o);
  }
  if ((h & 63) == 0) { sw[wid] = wv; swl[wid] = wl; }
  __syncthreads();
  if (h == 0) {
    float S1 = (sw[0] + sw[1]) + (sw[2] + sw[3]);
    float S2 = (swl[0] + swl[1]) + (swl[2] + swl[3]);
    out[b] = S2 / S1;                       // exp_loss
    out[BB + b] = lossArr[b * HH + mi];     // top_loss
    float4 p = ((const float4*)ws)[b * HH + mi];
    out[2 * BB + 3 * b + 0] = p.x;          // pred
    out[2 * BB + 3 * b + 1] = p.y;
    out[2 * BB + 3 * b + 2] = p.z;
  }
}

extern "C" void kernel_launch(void* const* d_in, const int* in_sizes, int n_in,
                              void* d_out, int out_size, void* d_ws, size_t ws_size,
                              hipStream_t stream) {
  const float* pts = (const float*)d_in[0];
  const float* target = (const float*)d_in[1];
  const int* sidx = (const int*)d_in[2];
  float* out = (float*)d_out;
  float* ws = (float*)d_ws;
  float* partial = ws + WS_PART_F;

  score_kernel<<<dim3(CC, BB), HH, 0, stream>>>(pts, target, sidx, ws, partial);
  finalize_kernel<<<BB, HH, 0, stream>>>(ws, out);
}

// Round 7
// 22.514 us; speedup vs baseline: 2.7558x; 1.0193x over previous
//
#include <hip/hip_runtime.h>
#include <math.h>

#define BB 32
#define HH 256
#define NN 8192
#define NC 8                  // chunks over N
#define PHALF 2               // plane halves
#define CHUNK (NN / NC)       // 1024 points per chunk
#define PPB (HH / PHALF)      // 128 planes per block
#define P 4                   // planes per thread
#define SUB (CHUNK / 8)       // 128 points per sub-range

// ws layout (floats):
//   planes : BB*HH*4 = 32768 floats at 0      (float4 per plane)
//   loss   : BB*HH   =  8192 floats at 32768
//   partial: BB*PHALF*NC*PPB = 65536 floats at 40960
#define WS_LOSS_F ((size_t)BB * HH * 4)
#define WS_PART_F (WS_LOSS_F + (size_t)BB * HH)

// Block = (128 planes, 1024-pt chunk). Waves 0-1 fit this block's 128 planes
// (scattered L2-hit gather) WHILE waves 2-3 stage the chunk via
// global_load_lds — the two latency phases overlap. No cross-block sync,
// no fences (rounds 2/4 lesson: __threadfence tails serialize the grid).
__global__ __launch_bounds__(256) void score_kernel(
    const float* __restrict__ pts, const float* __restrict__ target,
    const int* __restrict__ sidx, float* __restrict__ ws,
    float* __restrict__ partial) {
  const int bx = blockIdx.x;            // [0,16)
  const int ph = bx >> 3, chunk = bx & 7;
  const int b = blockIdx.y;
  const int h = threadIdx.x;

  __shared__ float4 smp[CHUNK * 3 / 4];   // 12 KB chunk points
  __shared__ float4 plane_lds[PPB];       // 2 KB planes (unscaled)
  __shared__ float scorepad[PPB * 9];     // 4.5 KB padded reduce pad

  if (h >= 128) {
    // ---- waves 2-3: async stage of 768 float4 (lane-contiguous dests) ----
    const float4* src4 =
        (const float4*)(pts + ((long)b * NN + (long)chunk * CHUNK) * 3);
    const int l = h - 128;
#pragma unroll
    for (int i = 0; i < 6; ++i) {
      __builtin_amdgcn_global_load_lds(src4 + l + 128 * i, &smp[l + 128 * i],
                                       16, 0, 0);
    }
  } else {
    // ---- waves 0-1: fit plane ph*128+h of batch b ----
    long ibase = ((long)b * HH + ph * PPB + h) * 3;
    int i0 = sidx[ibase], i1 = sidx[ibase + 1], i2 = sidx[ibase + 2];
    const float* pb = pts + (long)b * NN * 3;
    float p0x = pb[3 * i0], p0y = pb[3 * i0 + 1], p0z = pb[3 * i0 + 2];
    float p1x = pb[3 * i1], p1y = pb[3 * i1 + 1], p1z = pb[3 * i1 + 2];
    float p2x = pb[3 * i2], p2y = pb[3 * i2 + 1], p2z = pb[3 * i2 + 2];
    float v1x = p1x - p0x, v1y = p1y - p0y, v1z = p1z - p0z;
    float v2x = p2x - p0x, v2y = p2y - p0y, v2z = p2z - p0z;
    // explicit non-FMA cross product: degenerate triples must give EXACT
    // zero to match numpy's all_zero replacement path.
    float nx = __fsub_rn(__fmul_rn(v1y, v2z), __fmul_rn(v1z, v2y));
    float ny = __fsub_rn(__fmul_rn(v1z, v2x), __fmul_rn(v1x, v2z));
    float nz = __fsub_rn(__fmul_rn(v1x, v2y), __fmul_rn(v1y, v2x));
    float d = -(__fmul_rn(nx, p0x) + __fmul_rn(ny, p0y) + __fmul_rn(nz, p0z));
    if (nx == 0.0f && ny == 0.0f && nz == 0.0f && d == 0.0f) {
      nx = 1.0f; ny = 1.0f; nz = 1.0f; d = 1.0f;
    }
    // rsq + mul normalize (~1e-7 rel err; threshold is 0.17 — safe)
    float inv = __builtin_amdgcn_rsqf(nx * nx + ny * ny + nz * nz);
    nx *= inv; ny *= inv; nz *= inv; d *= inv;
    plane_lds[h] = make_float4(nx, ny, nz, d);

    if (chunk == 0) {  // one block per (batch, plane-half) persists
      ((float4*)ws)[b * HH + ph * PPB + h] = make_float4(nx, ny, nz, d);
      float tx = target[b * 3], ty = target[b * 3 + 1], tz = target[b * 3 + 2];
      float lm = (nx - tx) * (nx - tx) + (ny - ty) * (ny - ty) +
                 (nz - tz) * (nz - tz);
      float lp = (nx + tx) * (nx + tx) + (ny + ty) * (ny + ty) +
                 (nz + tz) * (nz + tz);
      ws[WS_LOSS_F + b * HH + ph * PPB + h] = fminf(lm, lp);
    }
  }
  __syncthreads();  // planes in LDS + points staged

  // ---- load P=4 planes, pre-scaled by sqrt(50*log2 e) ----
  const float SC = 8.4932180028801371f;
  const int pid = h & 31;
  const int s = h >> 5;  // point sub-range [0,8)
  float4 pls[P];
#pragma unroll
  for (int k = 0; k < P; ++k) {
    float4 q = plane_lds[pid + (k << 5)];
    pls[k] = make_float4(q.x * SC, q.y * SC, q.z * SC, q.w * SC);
  }

  // ---- score: 128 points x 4 planes per thread (2-addr broadcast reads) ----
  float acc[P];
#pragma unroll
  for (int k = 0; k < P; ++k) acc[k] = 0.f;
  const int sbase = s * (SUB * 3 / 4);  // 96 float4 per sub-range
#pragma unroll 4
  for (int g = 0; g < SUB / 4; ++g) {  // 4 points per iter
    float4 v0 = smp[sbase + 3 * g + 0];
    float4 v1 = smp[sbase + 3 * g + 1];
    float4 v2 = smp[sbase + 3 * g + 2];
#pragma unroll
    for (int k = 0; k < P; ++k) {
      float4 q = pls[k];
      float t0 = fmaf(q.x, v0.x, fmaf(q.y, v0.y, fmaf(q.z, v0.z, q.w)));
      float t1 = fmaf(q.x, v0.w, fmaf(q.y, v1.x, fmaf(q.z, v1.y, q.w)));
      float t2 = fmaf(q.x, v1.z, fmaf(q.y, v1.w, fmaf(q.z, v2.x, q.w)));
      float t3 = fmaf(q.x, v2.y, fmaf(q.y, v2.z, fmaf(q.z, v2.w, q.w)));
      float e0 = __builtin_amdgcn_exp2f(-(t0 * t0));
      float e1 = __builtin_amdgcn_exp2f(-(t1 * t1));
      float e2 = __builtin_amdgcn_exp2f(-(t2 * t2));
      float e3 = __builtin_amdgcn_exp2f(-(t3 * t3));
      acc[k] += (e0 + e1) + (e2 + e3);
    }
  }

  // ---- in-block reduce across sub-ranges (stride-9 pad, conflict-free) ----
#pragma unroll
  for (int k = 0; k < P; ++k) scorepad[(pid + (k << 5)) * 9 + s] = acc[k];
  __syncthreads();
  if (h < PPB) {
    float rowsum = 0.f;
#pragma unroll
    for (int j = 0; j < 8; ++j) rowsum += scorepad[h * 9 + j];
    partial[(((long)b * PHALF + ph) * NC + chunk) * PPB + h] = rowsum;
  }
}

__global__ __launch_bounds__(HH) void finalize_kernel(
    const float* __restrict__ ws, float* __restrict__ out) {
  int b = blockIdx.x, h = threadIdx.x;  // h = global plane id
  const float* lossArr = ws + WS_LOSS_F;
  const float* partial = ws + WS_PART_F;
  const int ph = h >> 7, idx = h & 127;
  float s = 0.f;
#pragma unroll
  for (int c = 0; c < NC; ++c)
    s += partial[(((long)b * PHALF + ph) * NC + c) * PPB + idx];
  float l = lossArr[b * HH + h];

  __shared__ float redv[4];
  __shared__ int redi[4];
  __shared__ float sw[4], swl[4];

  // ---- wave-level argmax via shuffles (first-index tie-break) ----
  float v = s; int vidx = h;
#pragma unroll
  for (int o = 32; o > 0; o >>= 1) {
    float ov = __shfl_xor(v, o);
    int oi = __shfl_xor(vidx, o);
    if (ov > v || (ov == v && oi < vidx)) { v = ov; vidx = oi; }
  }
  const int wid = h >> 6;
  if ((h & 63) == 0) { redv[wid] = v; redi[wid] = vidx; }
  __syncthreads();
  float m = redv[0]; int mi = redi[0];
#pragma unroll
  for (int w = 1; w < 4; ++w) {
    float ov = redv[w]; int oi = redi[w];
    if (ov > m || (ov == m && oi < mi)) { m = ov; mi = oi; }
  }

  // ---- softmax sums via shuffles ----
  const float HL = 0.72134752044448170f;  // 0.5 * log2(e)
  float wv = __builtin_amdgcn_exp2f(HL * (s - m));
  float wl = wv * l;
#pragma unroll
  for (int o = 32; o > 0; o >>= 1) {
    wv += __shfl_xor(wv, o);
    wl += __shfl_xor(wl, o);
  }
  if ((h & 63) == 0) { sw[wid] = wv; swl[wid] = wl; }
  __syncthreads();
  if (h == 0) {
    float S1 = (sw[0] + sw[1]) + (sw[2] + sw[3]);
    float S2 = (swl[0] + swl[1]) + (swl[2] + swl[3]);
    out[b] = S2 / S1;                       // exp_loss
    out[BB + b] = lossArr[b * HH + mi];     // top_loss
    float4 p = ((const float4*)ws)[b * HH + mi];
    out[2 * BB + 3 * b + 0] = p.x;          // pred
    out[2 * BB + 3 * b + 1] = p.y;
    out[2 * BB + 3 * b + 2] = p.z;
  }
}

extern "C" void kernel_launch(void* const* d_in, const int* in_sizes, int n_in,
                              void* d_out, int out_size, void* d_ws, size_t ws_size,
                              hipStream_t stream) {
  const float* pts = (const float*)d_in[0];
  const float* target = (const float*)d_in[1];
  const int* sidx = (const int*)d_in[2];
  float* out = (float*)d_out;
  float* ws = (float*)d_ws;
  float* partial = ws + WS_PART_F;

  score_kernel<<<dim3(PHALF * NC, BB), 256, 0, stream>>>(pts, target, sidx, ws,
                                                         partial);
  finalize_kernel<<<BB, HH, 0, stream>>>(ws, out);
}